// Round 5
// baseline (866.098 us; speedup 1.0000x reference)
//
#include <hip/hip_runtime.h>
#include <math.h>

#define BS 4
#define CC 28          // total channels in obs / maps
#define NF 25          // 1 + NUM_SEM splat feature channels
#define HS 240
#define WSC 320
#define NPIX (HS*WSC)
#define VR 100
#define ZD 80
#define MC 480
#define NCELL (VR*VR)                  // 10000 xy cells per batch
#define NREC_MAX ((size_t)BS*NPIX*4)   // worst-case records
#define NSTRIP 8192                    // accum workgroups (1 wave each)
#define ROWS 28                        // ahp row stride (25 feat + 1 allsum + 2 pad)
#define FSTR 32                        // feat row stride (24 used + 8 pad) = one 128B line
#define SBMAX 159                      // sb[] capacity - 1

__device__ __forceinline__ float clip01(float v){ return fminf(fmaxf(v, 0.f), 1.f); }

// ---------------- shared geometry (identical in prep/scatter) ----------------
struct Geo {
    float wx[2], wy[2], wz[2];
    int   xi[2], yi[2], zi[2];
    bool  sx[2], sy[2];
};

__device__ __forceinline__ Geo compute_geo(const float* __restrict__ obs,
                                           const float* __restrict__ view_angles,
                                           int b, int pix){
    int j = pix % WSC;
    int i = pix / WSC;
    float depth = obs[((size_t)(b*CC + 3))*NPIX + pix];
    if (depth < 0.f) depth = 10000.f;
    const float FOCAL = 277.12812921102035f;
    float X = ((float)j - 159.5f) * depth / FOCAL;
    float Z = ((float)(HS-1-i) - 119.5f) * depth / FOCAL;
    float a = view_angles[b] * 0.017453292519943295f;
    float ca = cosf(a), sa = sinf(a);
    float Y2 = ca*depth - sa*Z;
    float Z2 = sa*depth + ca*Z + 155.f;   // + AGENT_HEIGHT
    float X2 = X + 250.f;                 // + SHIFT_X

    // replicate reference arithmetic chain exactly
    float px = ((X2/5.f - 50.f)/100.f*2.f)*50.f + 50.f;
    float py = ((Y2/5.f - 50.f)/100.f*2.f)*50.f + 50.f;
    float pz = ((Z2/5.f - 32.f)/80.f*2.f)*40.f + 40.f;

    Geo g;
    float fx = floorf(px), fy = floorf(py), fz = floorf(pz);
    {
        float p0 = fx, p1 = fx + 1.f;
        g.sx[0] = (p0 > 0.f) && (p0 < 100.f);
        g.sx[1] = (p1 > 0.f) && (p1 < 100.f);
        g.wx[0] = g.sx[0] ? (1.f - fabsf(px - p0)) : 0.f;
        g.wx[1] = g.sx[1] ? (1.f - fabsf(px - p1)) : 0.f;
        g.xi[0] = g.sx[0] ? (int)p0 : 0;
        g.xi[1] = g.sx[1] ? (int)p1 : 0;
    }
    {
        float p0 = fy, p1 = fy + 1.f;
        g.sy[0] = (p0 > 0.f) && (p0 < 100.f);
        g.sy[1] = (p1 > 0.f) && (p1 < 100.f);
        g.wy[0] = g.sy[0] ? (1.f - fabsf(py - p0)) : 0.f;
        g.wy[1] = g.sy[1] ? (1.f - fabsf(py - p1)) : 0.f;
        g.yi[0] = g.sy[0] ? (int)p0 : 0;
        g.yi[1] = g.sy[1] ? (int)p1 : 0;
    }
    {
        float p0 = fz, p1 = fz + 1.f;
        bool s0 = (p0 > 0.f) && (p0 < 80.f);
        bool s1 = (p1 > 0.f) && (p1 < 80.f);
        g.wz[0] = s0 ? (1.f - fabsf(pz - p0)) : 0.f;
        g.wz[1] = s1 ? (1.f - fabsf(pz - p1)) : 0.f;
        g.zi[0] = s0 ? (int)p0 : 0;
        g.zi[1] = s1 ? (int)p1 : 0;
    }
    return g;
}

// ---------------- pose + sampling params ----------------
__global__ void pose_kernel(const float* __restrict__ pose_obs,
                            const float* __restrict__ poses_last,
                            float* __restrict__ out_p1,
                            float* __restrict__ out_p2,
                            float* __restrict__ params){
    int b = threadIdx.x;
    if (b >= BS) return;
    const float R2D = 57.29577951308232f;
    float th0 = poses_last[b*3+2] / R2D;
    float s0 = sinf(th0), c0 = cosf(th0);
    float ny = poses_last[b*3+1] + pose_obs[b*3+0]*s0 + pose_obs[b*3+1]*c0;
    float nx = poses_last[b*3+0] + pose_obs[b*3+0]*c0 - pose_obs[b*3+1]*s0;
    float no = poses_last[b*3+2] + pose_obs[b*3+2]*R2D;
    no = fmodf(no - 180.f, 360.f) + 180.f;
    no = fmodf(no + 180.f, 360.f) - 180.f;
    out_p1[b*3+0] = nx; out_p1[b*3+1] = ny; out_p1[b*3+2] = no;
    out_p2[b*3+0] = nx; out_p2[b*3+1] = ny; out_p2[b*3+2] = no;
    const float half = 240.f;
    float sx = -(nx*100.f/5.f - half)/half;
    float sy = -(ny*100.f/5.f - half)/half;
    float t = (90.f - no) * 0.017453292519943295f;
    params[b*4+0] = cosf(t);
    params[b*4+1] = sinf(t);
    params[b*4+2] = sx;
    params[b*4+3] = sy;
}

// ---------------- pass A: count records + transpose features ----------------
__global__ __launch_bounds__(256)
void prep_kernel(const float* __restrict__ obs,
                 const float* __restrict__ view_angles,
                 int* __restrict__ counts,
                 float* __restrict__ feat){
    __shared__ float sf[6400];          // 256 px * 24 f, padded stride 25
    int t   = threadIdx.x;
    int tid = blockIdx.x * 256 + t;
    int b   = tid / NPIX;
    int pix = tid % NPIX;

    Geo g = compute_geo(obs, view_angles, b, pix);
    #pragma unroll
    for (int cy = 0; cy < 2; ++cy)
    #pragma unroll
    for (int cx = 0; cx < 2; ++cx){
        if (g.sx[cx] && g.sy[cy] && (g.wx[cx]*g.wy[cy] != 0.f))
            atomicAdd(&counts[b*NCELL + g.yi[cy]*VR + g.xi[cx]], 1);
    }

    #pragma unroll 6
    for (int f = 0; f < 24; ++f)
        sf[t*25 + f] = obs[((size_t)(b*CC + 4 + f))*NPIX + pix];
    __syncthreads();
    // coalesced write-out: feat rows stride 32 (one 128B line per pixel)
    size_t base = ((size_t)b*NPIX + (size_t)(pix - t)) * FSTR;
    for (int q = t; q < 256*FSTR; q += 256){
        int pl = q >> 5, ff = q & 31;
        feat[base + q] = (ff < 24) ? sf[pl*25 + ff] : 0.f;
    }
}

// ---------------- pass B: dual (count,weight) scan + strip assignment ----------------
__global__ void scan_kernel(const int* __restrict__ counts,
                            int* __restrict__ bases,      // TOT+1
                            int* __restrict__ cursor,
                            int* __restrict__ cell_start){ // NSTRIP+1
    __shared__ int partC[1024], partW[1024];
    int t = threadIdx.x;
    const int TOT = BS*NCELL;       // 40000
    const int CH  = 40;
    int beg = t*CH;
    int sc = 0, sw = 0;
    for (int i = 0; i < CH; ++i){
        int idx = beg + i;
        if (idx < TOT){ int c = counts[idx]; sc += c; sw += c + (c ? 24 : 6); }
    }
    partC[t] = sc; partW[t] = sw;
    __syncthreads();
    for (int off = 1; off < 1024; off <<= 1){
        int vc = (t >= off) ? partC[t-off] : 0;
        int vw = (t >= off) ? partW[t-off] : 0;
        __syncthreads();
        partC[t] += vc; partW[t] += vw;
        __syncthreads();
    }
    int totw  = partW[1023];
    int quota = (totw + NSTRIP - 1) / NSTRIP;
    if (quota < 1) quota = 1;
    int runC = (t == 0) ? 0 : partC[t-1];
    int runW = (t == 0) ? 0 : partW[t-1];
    if (t == 0) cell_start[0] = 0;
    for (int i = 0; i < CH; ++i){
        int idx = beg + i;
        if (idx >= TOT) break;
        int c = counts[idx];
        bases[idx]  = runC;
        cursor[idx] = runC;
        int w = c + (c ? 24 : 6);
        int sCur = runW / quota; if (sCur > NSTRIP-1) sCur = NSTRIP-1;
        runC += c; runW += w;
        int sNext = runW / quota; if (sNext > NSTRIP-1) sNext = NSTRIP-1;
        if (idx == TOT-1){
            bases[TOT] = runC;
            for (int gg = sCur+1; gg <= NSTRIP; ++gg) cell_start[gg] = TOT;
        } else {
            for (int gg = sCur+1; gg <= sNext; ++gg) cell_start[gg] = idx+1;
        }
    }
}

// ---------------- pass C: scatter self-contained records ----------------
__global__ __launch_bounds__(256)
void scatter_kernel(const float* __restrict__ obs,
                    const float* __restrict__ view_angles,
                    int* __restrict__ cursor,
                    uint4* __restrict__ records){
    int tid = blockIdx.x * 256 + threadIdx.x;
    int b   = tid / NPIX;
    int pix = tid % NPIX;
    Geo g = compute_geo(obs, view_angles, b, pix);
    #pragma unroll
    for (int cy = 0; cy < 2; ++cy)
    #pragma unroll
    for (int cx = 0; cx < 2; ++cx){
        float wxy = g.wx[cx] * g.wy[cy];
        if (g.sx[cx] && g.sy[cy] && (wxy != 0.f)){
            int cid = b*NCELL + g.yi[cy]*VR + g.xi[cx];
            int pos = atomicAdd(&cursor[cid], 1);
            float w0 = wxy * g.wz[0];
            float w1 = wxy * g.wz[1];
            unsigned iw = (unsigned)pix | ((unsigned)g.zi[0] << 17)
                                        | ((unsigned)g.zi[1] << 24);
            records[pos] = make_uint4(__float_as_uint(w0), __float_as_uint(w1), iw, 0u);
        }
    }
}

// ---------------- pass D: register-lean MLP pipeline, single-wave strips ----------------
// v5 (resubmit after infra failure): v4's pipeline spilled (VGPR capped at 64,
// +64MB scratch WRITE) and lost cross-cell feat L2 reuse (corner cells land on
// other XCDs). Fixes: only v[8] per batch in regs (re-read srec from LDS at
// flush), no min-wave launch bound, feat rows padded to one 128B line,
// XCD-chunked strip swizzle so neighboring cell rows share an XCD L2.

#define GATHERV(V, SUB) \
  _Pragma("unroll") \
  for (int u = 0; u < 8; ++u){ \
    int idx = (SUB) + 2*u + rr; \
    V[u] = 1.f; \
    if (flane && idx < n && f != 0){ \
      int pixq = (int)(srec[idx].z & 0x1FFFFu); \
      V[u] = feat_b[(size_t)pixq*FSTR + (f-1)]; } }

#define FLUSHV(V, SUB) \
  _Pragma("unroll") \
  for (int u = 0; u < 8; ++u){ \
    int idx = (SUB) + 2*u + rr; \
    if (flane && idx < n){ \
      uint4 rv = srec[idx]; \
      float w0 = __uint_as_float(rv.x), w1 = __uint_as_float(rv.y); \
      int z0 = (int)((rv.z >> 17) & 0x7Fu); \
      int z1 = (int)((rv.z >> 24) & 0x7Fu); \
      if (w0 != 0.f) atomicAdd(&col[z0*NF + f], V[u]*w0); \
      if (w1 != 0.f) atomicAdd(&col[z1*NF + f], V[u]*w1); } }

__global__ __launch_bounds__(64)
void accum_kernel(const uint4* __restrict__ records,
                  const float* __restrict__ feat,
                  const int* __restrict__ bases,       // TOT+1
                  const int* __restrict__ cell_start,  // NSTRIP+1
                  float* __restrict__ ahp,             // [BS*NCELL][ROWS]
                  float* __restrict__ out0){
    __shared__ float col[ZD*NF];        // 2000 floats (8 KB)
    __shared__ uint4 srec[64];          // 1 KB record chunk
    __shared__ int   sb[SBMAX+1];       // strip bases

    // XCD-chunked swizzle: consecutive strips (adjacent cell rows) -> same XCD
    int g0 = blockIdx.x;
    int g  = (g0 & 7)*(NSTRIP/8) + (g0 >> 3);
    int t  = threadIdx.x;
    int c0 = cell_start[g];
    int c1 = cell_start[g+1];
    int nc = c1 - c0;
    if (nc <= 0) return;
    if (nc > SBMAX) nc = SBMAX;         // defensive clamp (unreachable: quota>=6/cell)
    int f  = t & 31;
    int rr = t >> 5;
    bool flane = (f < NF);

    for (int i = t; i <= nc; i += 64) sb[i] = bases[c0 + i];
    {   float4* c4 = (float4*)col;
        #pragma unroll
        for (int i = 0; i < 8; ++i){ int idx = t + i*64; if (idx < 500) c4[idx] = make_float4(0,0,0,0); } }

    const uint4 Zq = make_uint4(0u,0u,0u,0u);
    uint4 cur = Zq;
    bool pf = false;

    for (int ci = 0; ci < nc; ++ci){
        int start = sb[ci], end = sb[ci+1];
        int cid = c0 + ci;
        if (start >= end){
            float* row = ahp + (size_t)cid*ROWS;
            if (t < ROWS) row[t] = 0.f;
            if (t == 0)  out0[cid] = 0.f;
            continue;
        }
        int b = cid / NCELL;
        const float* feat_b = feat + (size_t)b*NPIX*FSTR;

        if (!pf){
            int n0 = end - start; if (n0 > 64) n0 = 64;
            cur = (t < n0) ? records[start + t] : Zq;
        }
        pf = false;

        for (int cb = start; cb < end; cb += 64){
            int n = end - cb; if (n > 64) n = 64;
            srec[t] = cur;
            if (cb + 64 < end){
                int n2 = end - cb - 64; if (n2 > 64) n2 = 64;
                cur = (t < n2) ? records[cb + 64 + t] : Zq;
            } else if (ci + 1 < nc){
                int s2 = sb[ci+1], e2 = sb[ci+2];
                if (s2 < e2){
                    int n2 = e2 - s2; if (n2 > 64) n2 = 64;
                    cur = (t < n2) ? records[s2 + t] : Zq;
                    pf = true;
                }
            }
            // pipelined 16-record batches: gather(next) issued before flush(cur)
            float vA[8], vB[8];
            GATHERV(vA, 0);
            for (int sub = 0; sub < n; ){
                int nx = sub + 16;
                if (nx < n) GATHERV(vB, nx);
                FLUSHV(vA, sub);
                sub = nx; if (sub >= n) break;
                nx = sub + 16;
                if (nx < n) GATHERV(vA, nx);
                FLUSHV(vB, sub);
                sub = nx;
            }
        }

        // projection: lanes 0..49 = (f2 = lane%25, q = lane/25), q z-halves
        {
            int f2 = t % NF, q = t / NF;
            float sall = 0.f, sag = 0.f;
            if (t < 50){
                for (int z = q*40; z < q*40 + 40; ++z){
                    float rv = rintf(col[z*NF + f2]);
                    sall += rv;
                    if (z >= 11 && z < 49) sag += rv;   // agent-height z range
                }
            }
            float sall_o = __shfl(sall, (t + 25) & 63, 64);
            float sag_o  = __shfl(sag,  (t + 25) & 63, 64);
            float* row = ahp + (size_t)cid*ROWS;
            if (t < NF){
                float a = sag + sag_o;
                float s = sall + sall_o;
                row[t] = a;
                if (t == 0){
                    row[25] = s;
                    out0[cid] = clip01(a);
                }
            } else if (t == 26 || t == 27){
                row[t] = 0.f;
            }
        }
        // clear col for next cell (after projection reads it)
        {   float4* c4 = (float4*)col;
            #pragma unroll
            for (int i = 0; i < 8; ++i){ int idx = t + i*64; if (idx < 500) c4[idx] = make_float4(0,0,0,0); } }
    }
}

// ---------------- fused rotate+translate grid_sample + max ----------------
__global__ __launch_bounds__(256)
void final_kernel(const float* __restrict__ ahp,
                  const float* __restrict__ params,
                  const float* __restrict__ maps_last,
                  float* __restrict__ out1){
    int tid = blockIdx.x * blockDim.x + threadIdx.x;
    if (tid >= BS*MC*MC) return;
    int w = tid % MC;
    int h = (tid / MC) % MC;
    int b = tid / (MC*MC);

    float ct = params[b*4+0], st = params[b*4+1];
    float sx = params[b*4+2], sy = params[b*4+3];

    float gx = -1.f + 2.f*(float)w/479.f;
    float gy = -1.f + 2.f*(float)h/479.f;
    float ix = (gx + sx + 1.f)*0.5f*479.f;
    float iy = (gy + sy + 1.f)*0.5f*479.f;
    float x0 = floorf(ix), y0 = floorf(iy);
    float wx1 = ix - x0, wx0 = 1.f - wx1;
    float wy1 = iy - y0, wy0 = 1.f - wy1;

    int   offs[16];
    float wt16[16];
    int nz = 0;
    #pragma unroll
    for (int tc = 0; tc < 4; ++tc){
        float txf = (tc & 1) ? x0 + 1.f : x0;
        float tyf = (tc & 2) ? y0 + 1.f : y0;
        float wt  = ((tc & 1) ? wx1 : wx0) * ((tc & 2) ? wy1 : wy0);
        bool validT = (txf >= 0.f) && (txf <= 479.f) && (tyf >= 0.f) && (tyf <= 479.f);
        int txc = (int)fminf(fmaxf(txf, 0.f), 479.f);
        int tyc = (int)fminf(fmaxf(tyf, 0.f), 479.f);

        float gx2 = -1.f + 2.f*(float)txc/479.f;
        float gy2 = -1.f + 2.f*(float)tyc/479.f;
        float rgx = ct*gx2 - st*gy2;
        float rgy = st*gx2 + ct*gy2;
        float ixr = (rgx + 1.f)*0.5f*479.f;
        float iyr = (rgy + 1.f)*0.5f*479.f;
        float rx0 = floorf(ixr), ry0 = floorf(iyr);
        float rwx1 = ixr - rx0, rwx0 = 1.f - rwx1;
        float rwy1 = iyr - ry0, rwy0 = 1.f - rwy1;

        #pragma unroll
        for (int rc = 0; rc < 4; ++rc){
            int id = tc*4 + rc;
            float rxf = (rc & 1) ? rx0 + 1.f : rx0;
            float ryf = (rc & 2) ? ry0 + 1.f : ry0;
            float wr  = ((rc & 1) ? rwx1 : rwx0) * ((rc & 2) ? rwy1 : rwy0);
            bool validR = (rxf >= 0.f) && (rxf <= 479.f) && (ryf >= 0.f) && (ryf <= 479.f);
            int rxc = (int)fminf(fmaxf(rxf, 0.f), 479.f);
            int ryc = (int)fminf(fmaxf(ryf, 0.f), 479.f);
            bool inwin = validT && validR &&
                         (rxc >= 190) && (rxc < 290) && (ryc >= 240) && (ryc < 336);
            float wgt = wt * wr;
            if (inwin && wgt != 0.f){
                offs[id] = (ryc - 240)*VR + (rxc - 190);
                wt16[id] = wgt;
                nz++;
            } else {
                offs[id] = -1;
                wt16[id] = 0.f;
            }
        }
    }

    size_t outBase = (size_t)b*CC*MC*MC + (size_t)h*MC + w;
    if (nz == 0){
        #pragma unroll
        for (int ch = 0; ch < CC; ++ch){
            size_t o = outBase + (size_t)ch*MC*MC;
            out1[o] = fmaxf(maps_last[o], 0.f);
        }
        return;
    }

    const float* ahp_b = ahp + (size_t)b*NCELL*ROWS;
    float acc[26];
    #pragma unroll
    for (int k = 0; k < 26; ++k) acc[k] = 0.f;

    #pragma unroll
    for (int id = 0; id < 16; ++id){
        if (offs[id] < 0) continue;
        float v[28];
        {
            const float4* rp = (const float4*)(ahp_b + (size_t)offs[id]*ROWS);
            #pragma unroll
            for (int k = 0; k < 7; ++k){
                float4 r = rp[k];
                v[4*k]   = r.x; v[4*k+1] = r.y;
                v[4*k+2] = r.z; v[4*k+3] = r.w;
            }
        }
        float wgt = wt16[id];
        acc[0] += wgt * clip01(v[0]);       // fp_map_pred channel
        acc[1] += wgt * clip01(v[25]);      // exp_pred channel (all-height sum)
        #pragma unroll
        for (int ff = 1; ff < 25; ++ff)
            acc[1+ff] += wgt * clip01(v[ff] / 5.f);
    }

    #pragma unroll
    for (int ch = 0; ch < CC; ++ch){
        float a;
        if (ch == 0)      a = acc[0];
        else if (ch == 1) a = acc[1];
        else if (ch < 4)  a = 0.f;
        else              a = acc[ch-2];    // ch>=4 -> acc[1+(ch-3)]
        size_t o = outBase + (size_t)ch*MC*MC;
        out1[o] = fmaxf(maps_last[o], a);
    }
}

extern "C" void kernel_launch(void* const* d_in, const int* in_sizes, int n_in,
                              void* d_out, int out_size, void* d_ws, size_t ws_size,
                              hipStream_t stream){
    const float* obs         = (const float*)d_in[0];
    const float* pose_obs    = (const float*)d_in[1];
    const float* maps_last   = (const float*)d_in[2];
    const float* poses_last  = (const float*)d_in[3];
    const float* view_angles = (const float*)d_in[4];
    float* out = (float*)d_out;

    const size_t OUT0 = (size_t)BS*VR*VR;        // 40000
    const size_t OUT1 = (size_t)BS*CC*MC*MC;     // 25,804,800
    float* out0 = out;
    float* out1 = out + OUT0;
    float* out2 = out + OUT0 + OUT1;
    float* out3 = out2 + BS*3;

    const size_t AHP_FLOATS  = (size_t)BS*NCELL*ROWS; // 1,120,000 (4.48 MB)
    const size_t NCID        = (size_t)BS*NCELL;      // 40,000
    const size_t FEAT_FLOATS = (size_t)BS*NPIX*FSTR;  // 9,830,400 (39.3 MB)
    const size_t CS_INTS     = NSTRIP + 1;            // 8193

    // small arrays read by final_kernel — always in ws
    float* ahp    = (float*)d_ws;
    float* params = ahp + AHP_FLOATS;
    char*  ws_tail = (char*)(params + 16);
    size_t ws_used_small = (size_t)(ws_tail - (char*)d_ws);

    // big transient arrays: counts + bases(TOT+1) + cursor + cell_start + records + feat
    const size_t BIG_BYTES = (NCID*3 + 1 + CS_INTS)*4 + 64 + NREC_MAX*16 + FEAT_FLOATS*4;
    char* big;
    if (ws_size >= ws_used_small + BIG_BYTES){
        big = ws_tail;
    } else {
        // place in the tail of out1 (fully consumed before final_kernel writes out1)
        big = (char*)(out1 + OUT1) - BIG_BYTES;
        big = (char*)((uintptr_t)big & ~(uintptr_t)15);
    }
    int* counts     = (int*)big;
    int* bases      = counts + NCID;          // NCID+1 entries
    int* cursor     = bases + NCID + 1;
    int* cell_start = cursor + NCID;
    uint4* records = (uint4*)(((uintptr_t)(cell_start + CS_INTS) + 15) & ~(uintptr_t)15);
    float* feat    = (float*)(records + NREC_MAX);

    hipMemsetAsync(counts, 0, NCID*4, stream);
    pose_kernel<<<1, 64, 0, stream>>>(pose_obs, poses_last, out2, out3, params);

    int nblk = (BS*NPIX)/256;   // 1200, exact
    prep_kernel<<<nblk, 256, 0, stream>>>(obs, view_angles, counts, feat);
    scan_kernel<<<1, 1024, 0, stream>>>(counts, bases, cursor, cell_start);
    scatter_kernel<<<nblk, 256, 0, stream>>>(obs, view_angles, cursor, records);
    accum_kernel<<<NSTRIP, 64, 0, stream>>>(records, feat, bases, cell_start,
                                            ahp, out0);
    final_kernel<<<(BS*MC*MC + 255)/256, 256, 0, stream>>>(ahp, params,
                                                           maps_last, out1);
}

// Round 6
// 849.331 us; speedup vs baseline: 1.0197x; 1.0197x over previous
//
#include <hip/hip_runtime.h>
#include <math.h>

#define BS 4
#define CC 28          // total channels in obs / maps
#define NF 25          // 1 + NUM_SEM splat feature channels
#define HS 240
#define WSC 320
#define NPIX (HS*WSC)
#define VR 100
#define ZD 80
#define MC 480
#define NCELL (VR*VR)                  // 10000 xy cells per batch
#define NREC_MAX ((size_t)BS*NPIX*4)   // worst-case records
#define NSTRIP 8192                    // accum workgroups (1 wave each)
#define ROWS 28                        // ahp row stride (25 feat + 1 allsum + 2 pad)
#define FSTR 32                        // feat row stride (24 used + 8 pad) = one 128B line
#define SBMAX 159                      // sb[] capacity - 1

__device__ __forceinline__ float clip01(float v){ return fminf(fmaxf(v, 0.f), 1.f); }
__device__ __forceinline__ unsigned rl(unsigned v, int k){
    return (unsigned)__builtin_amdgcn_readlane((int)v, k);
}

// ---------------- shared geometry (identical in prep/scatter) ----------------
struct Geo {
    float wx[2], wy[2], wz[2];
    int   xi[2], yi[2], zi[2];
    bool  sx[2], sy[2];
};

__device__ __forceinline__ Geo compute_geo(const float* __restrict__ obs,
                                           const float* __restrict__ view_angles,
                                           int b, int pix){
    int j = pix % WSC;
    int i = pix / WSC;
    float depth = obs[((size_t)(b*CC + 3))*NPIX + pix];
    if (depth < 0.f) depth = 10000.f;
    const float FOCAL = 277.12812921102035f;
    float X = ((float)j - 159.5f) * depth / FOCAL;
    float Z = ((float)(HS-1-i) - 119.5f) * depth / FOCAL;
    float a = view_angles[b] * 0.017453292519943295f;
    float ca = cosf(a), sa = sinf(a);
    float Y2 = ca*depth - sa*Z;
    float Z2 = sa*depth + ca*Z + 155.f;   // + AGENT_HEIGHT
    float X2 = X + 250.f;                 // + SHIFT_X

    // replicate reference arithmetic chain exactly
    float px = ((X2/5.f - 50.f)/100.f*2.f)*50.f + 50.f;
    float py = ((Y2/5.f - 50.f)/100.f*2.f)*50.f + 50.f;
    float pz = ((Z2/5.f - 32.f)/80.f*2.f)*40.f + 40.f;

    Geo g;
    float fx = floorf(px), fy = floorf(py), fz = floorf(pz);
    {
        float p0 = fx, p1 = fx + 1.f;
        g.sx[0] = (p0 > 0.f) && (p0 < 100.f);
        g.sx[1] = (p1 > 0.f) && (p1 < 100.f);
        g.wx[0] = g.sx[0] ? (1.f - fabsf(px - p0)) : 0.f;
        g.wx[1] = g.sx[1] ? (1.f - fabsf(px - p1)) : 0.f;
        g.xi[0] = g.sx[0] ? (int)p0 : 0;
        g.xi[1] = g.sx[1] ? (int)p1 : 0;
    }
    {
        float p0 = fy, p1 = fy + 1.f;
        g.sy[0] = (p0 > 0.f) && (p0 < 100.f);
        g.sy[1] = (p1 > 0.f) && (p1 < 100.f);
        g.wy[0] = g.sy[0] ? (1.f - fabsf(py - p0)) : 0.f;
        g.wy[1] = g.sy[1] ? (1.f - fabsf(py - p1)) : 0.f;
        g.yi[0] = g.sy[0] ? (int)p0 : 0;
        g.yi[1] = g.sy[1] ? (int)p1 : 0;
    }
    {
        float p0 = fz, p1 = fz + 1.f;
        bool s0 = (p0 > 0.f) && (p0 < 80.f);
        bool s1 = (p1 > 0.f) && (p1 < 80.f);
        g.wz[0] = s0 ? (1.f - fabsf(pz - p0)) : 0.f;
        g.wz[1] = s1 ? (1.f - fabsf(pz - p1)) : 0.f;
        g.zi[0] = s0 ? (int)p0 : 0;
        g.zi[1] = s1 ? (int)p1 : 0;
    }
    return g;
}

// ---------------- pose + sampling params ----------------
__global__ void pose_kernel(const float* __restrict__ pose_obs,
                            const float* __restrict__ poses_last,
                            float* __restrict__ out_p1,
                            float* __restrict__ out_p2,
                            float* __restrict__ params){
    int b = threadIdx.x;
    if (b >= BS) return;
    const float R2D = 57.29577951308232f;
    float th0 = poses_last[b*3+2] / R2D;
    float s0 = sinf(th0), c0 = cosf(th0);
    float ny = poses_last[b*3+1] + pose_obs[b*3+0]*s0 + pose_obs[b*3+1]*c0;
    float nx = poses_last[b*3+0] + pose_obs[b*3+0]*c0 - pose_obs[b*3+1]*s0;
    float no = poses_last[b*3+2] + pose_obs[b*3+2]*R2D;
    no = fmodf(no - 180.f, 360.f) + 180.f;
    no = fmodf(no + 180.f, 360.f) - 180.f;
    out_p1[b*3+0] = nx; out_p1[b*3+1] = ny; out_p1[b*3+2] = no;
    out_p2[b*3+0] = nx; out_p2[b*3+1] = ny; out_p2[b*3+2] = no;
    const float half = 240.f;
    float sx = -(nx*100.f/5.f - half)/half;
    float sy = -(ny*100.f/5.f - half)/half;
    float t = (90.f - no) * 0.017453292519943295f;
    params[b*4+0] = cosf(t);
    params[b*4+1] = sinf(t);
    params[b*4+2] = sx;
    params[b*4+3] = sy;
}

// ---------------- pass A: count records + transpose features ----------------
__global__ __launch_bounds__(256)
void prep_kernel(const float* __restrict__ obs,
                 const float* __restrict__ view_angles,
                 int* __restrict__ counts,
                 float* __restrict__ feat){
    __shared__ float sf[6400];          // 256 px * 24 f, padded stride 25
    int t   = threadIdx.x;
    int tid = blockIdx.x * 256 + t;
    int b   = tid / NPIX;
    int pix = tid % NPIX;

    Geo g = compute_geo(obs, view_angles, b, pix);
    #pragma unroll
    for (int cy = 0; cy < 2; ++cy)
    #pragma unroll
    for (int cx = 0; cx < 2; ++cx){
        if (g.sx[cx] && g.sy[cy] && (g.wx[cx]*g.wy[cy] != 0.f))
            atomicAdd(&counts[b*NCELL + g.yi[cy]*VR + g.xi[cx]], 1);
    }

    #pragma unroll 6
    for (int f = 0; f < 24; ++f)
        sf[t*25 + f] = obs[((size_t)(b*CC + 4 + f))*NPIX + pix];
    __syncthreads();
    // coalesced write-out: feat rows stride 32 (one 128B line per pixel)
    size_t base = ((size_t)b*NPIX + (size_t)(pix - t)) * FSTR;
    for (int q = t; q < 256*FSTR; q += 256){
        int pl = q >> 5, ff = q & 31;
        feat[base + q] = (ff < 24) ? sf[pl*25 + ff] : 0.f;
    }
}

// ---------------- pass B: dual (count,weight) scan + strip assignment ----------------
__global__ void scan_kernel(const int* __restrict__ counts,
                            int* __restrict__ bases,      // TOT+1
                            int* __restrict__ cursor,
                            int* __restrict__ cell_start){ // NSTRIP+1
    __shared__ int partC[1024], partW[1024];
    int t = threadIdx.x;
    const int TOT = BS*NCELL;       // 40000
    const int CH  = 40;
    int beg = t*CH;
    int sc = 0, sw = 0;
    for (int i = 0; i < CH; ++i){
        int idx = beg + i;
        if (idx < TOT){ int c = counts[idx]; sc += c; sw += c + (c ? 24 : 6); }
    }
    partC[t] = sc; partW[t] = sw;
    __syncthreads();
    for (int off = 1; off < 1024; off <<= 1){
        int vc = (t >= off) ? partC[t-off] : 0;
        int vw = (t >= off) ? partW[t-off] : 0;
        __syncthreads();
        partC[t] += vc; partW[t] += vw;
        __syncthreads();
    }
    int totw  = partW[1023];
    int quota = (totw + NSTRIP - 1) / NSTRIP;
    if (quota < 1) quota = 1;
    int runC = (t == 0) ? 0 : partC[t-1];
    int runW = (t == 0) ? 0 : partW[t-1];
    if (t == 0) cell_start[0] = 0;
    for (int i = 0; i < CH; ++i){
        int idx = beg + i;
        if (idx >= TOT) break;
        int c = counts[idx];
        bases[idx]  = runC;
        cursor[idx] = runC;
        int w = c + (c ? 24 : 6);
        int sCur = runW / quota; if (sCur > NSTRIP-1) sCur = NSTRIP-1;
        runC += c; runW += w;
        int sNext = runW / quota; if (sNext > NSTRIP-1) sNext = NSTRIP-1;
        if (idx == TOT-1){
            bases[TOT] = runC;
            for (int gg = sCur+1; gg <= NSTRIP; ++gg) cell_start[gg] = TOT;
        } else {
            for (int gg = sCur+1; gg <= sNext; ++gg) cell_start[gg] = idx+1;
        }
    }
}

// ---------------- pass C: scatter self-contained records ----------------
__global__ __launch_bounds__(256)
void scatter_kernel(const float* __restrict__ obs,
                    const float* __restrict__ view_angles,
                    int* __restrict__ cursor,
                    uint4* __restrict__ records){
    int tid = blockIdx.x * 256 + threadIdx.x;
    int b   = tid / NPIX;
    int pix = tid % NPIX;
    Geo g = compute_geo(obs, view_angles, b, pix);
    #pragma unroll
    for (int cy = 0; cy < 2; ++cy)
    #pragma unroll
    for (int cx = 0; cx < 2; ++cx){
        float wxy = g.wx[cx] * g.wy[cy];
        if (g.sx[cx] && g.sy[cy] && (wxy != 0.f)){
            int cid = b*NCELL + g.yi[cy]*VR + g.xi[cx];
            int pos = atomicAdd(&cursor[cid], 1);
            float w0 = wxy * g.wz[0];
            float w1 = wxy * g.wz[1];
            unsigned iw = (unsigned)pix | ((unsigned)g.zi[0] << 17)
                                        | ((unsigned)g.zi[1] << 24);
            records[pos] = make_uint4(__float_as_uint(w0), __float_as_uint(w1), iw, 0u);
        }
    }
}

// ---------------- pass D: readlane-broadcast accumulation, single-wave strips ----------------
// v6: accum is LDS/TA pipe-bound (~60 cy of shared per-CU pipe time per record;
// invariant across v1-v5 scheduling changes). Remove ALL srec LDS traffic:
// records stay in the chunk-load registers and are broadcast per-record with
// v_readlane (VALU). Only the 2 irreducible ds_adds remain on the LDS pipe;
// feat gathers become scalar-base+lane coalesced single-line loads.
__global__ __launch_bounds__(64)
void accum_kernel(const uint4* __restrict__ records,
                  const float* __restrict__ feat,
                  const int* __restrict__ bases,       // TOT+1
                  const int* __restrict__ cell_start,  // NSTRIP+1
                  float* __restrict__ ahp,             // [BS*NCELL][ROWS]
                  float* __restrict__ out0){
    __shared__ float col[ZD*NF];        // 2000 floats (8 KB)
    __shared__ int   sb[SBMAX+1];       // strip bases

    // XCD-chunked swizzle: consecutive strips (adjacent cell rows) -> same XCD
    int g0 = blockIdx.x;
    int g  = (g0 & 7)*(NSTRIP/8) + (g0 >> 3);
    int t  = threadIdx.x;
    int c0 = cell_start[g];
    int c1 = cell_start[g+1];
    int nc = c1 - c0;
    if (nc <= 0) return;
    if (nc > SBMAX) nc = SBMAX;         // defensive clamp (unreachable: quota>=6/cell)
    int f  = t & 31;
    int rr = t >> 5;
    bool flane = (f < NF);

    for (int i = t; i <= nc; i += 64) sb[i] = bases[c0 + i];
    {   float4* c4 = (float4*)col;
        #pragma unroll
        for (int i = 0; i < 8; ++i){ int idx = t + i*64; if (idx < 500) c4[idx] = make_float4(0,0,0,0); } }

    const uint4 Zq = make_uint4(0u,0u,0u,0u);

    for (int ci = 0; ci < nc; ++ci){
        int start = sb[ci], end = sb[ci+1];
        int cid = c0 + ci;
        if (start >= end){
            float* row = ahp + (size_t)cid*ROWS;
            if (t < ROWS) row[t] = 0.f;
            if (t == 0)  out0[cid] = 0.f;
            continue;
        }
        int b = cid / NCELL;
        const float* feat_b = feat + (size_t)b*NPIX*FSTR;

        int cb = start;
        int n  = end - start; if (n > 64) n = 64;
        uint4 cur = (t < n) ? records[start + t] : Zq;

        while (cb < end){
            // prefetch next chunk while processing this one
            int nb = cb + 64;
            uint4 nxt = Zq; int n2 = 0;
            if (nb < end){
                n2 = end - nb; if (n2 > 64) n2 = 64;
                nxt = (t < n2) ? records[nb + t] : Zq;
            }

            // 4 records per iteration: pair P (k,k+1) on rr halves, pair Q (k+2,k+3)
            for (int k = 0; k < n; k += 4){
                int p1 = (k+1 < n) ? k+1 : k;  bool pv1 = (k+1 < n);
                int q0 = (k+2 < n) ? k+2 : k;  bool qv0 = (k+2 < n);
                int q1 = (k+3 < n) ? k+3 : k;  bool qv1 = (k+3 < n);

                unsigned pxa = rl(cur.x,k),  pya = rl(cur.y,k),  pza = rl(cur.z,k);
                unsigned pxb = rl(cur.x,p1), pyb = rl(cur.y,p1), pzb = rl(cur.z,p1);
                if (!pv1){ pxb = 0u; pyb = 0u; }
                unsigned qxa = rl(cur.x,q0), qya = rl(cur.y,q0), qza = rl(cur.z,q0);
                if (!qv0){ qxa = 0u; qya = 0u; }
                unsigned qxb = rl(cur.x,q1), qyb = rl(cur.y,q1), qzb = rl(cur.z,q1);
                if (!qv1){ qxb = 0u; qyb = 0u; }

                float    pw0 = __uint_as_float(rr ? pxb : pxa);
                float    pw1 = __uint_as_float(rr ? pyb : pya);
                unsigned piw = rr ? pzb : pza;
                float    qw0 = __uint_as_float(rr ? qxb : qxa);
                float    qw1 = __uint_as_float(rr ? qyb : qya);
                unsigned qiw = rr ? qzb : qza;

                int ppix = (int)(piw & 0x1FFFFu);
                int qpix = (int)(qiw & 0x1FFFFu);

                // issue both gathers before any use
                float pval = 1.f, qval = 1.f;
                if (flane && f != 0){
                    pval = feat_b[(size_t)ppix*FSTR + (f-1)];
                    qval = feat_b[(size_t)qpix*FSTR + (f-1)];
                }
                if (flane){
                    int z;
                    z = (int)((piw >> 17) & 0x7Fu); if (pw0 != 0.f) atomicAdd(&col[z*NF + f], pval*pw0);
                    z = (int)((piw >> 24) & 0x7Fu); if (pw1 != 0.f) atomicAdd(&col[z*NF + f], pval*pw1);
                    z = (int)((qiw >> 17) & 0x7Fu); if (qw0 != 0.f) atomicAdd(&col[z*NF + f], qval*qw0);
                    z = (int)((qiw >> 24) & 0x7Fu); if (qw1 != 0.f) atomicAdd(&col[z*NF + f], qval*qw1);
                }
            }
            cur = nxt; n = n2; cb = nb;
        }

        // projection: lanes 0..49 = (f2 = lane%25, q = lane/25), q z-halves
        {
            int f2 = t % NF, q = t / NF;
            float sall = 0.f, sag = 0.f;
            if (t < 50){
                for (int z = q*40; z < q*40 + 40; ++z){
                    float rv = rintf(col[z*NF + f2]);
                    sall += rv;
                    if (z >= 11 && z < 49) sag += rv;   // agent-height z range
                }
            }
            float sall_o = __shfl(sall, (t + 25) & 63, 64);
            float sag_o  = __shfl(sag,  (t + 25) & 63, 64);
            float* row = ahp + (size_t)cid*ROWS;
            if (t < NF){
                float a = sag + sag_o;
                float s = sall + sall_o;
                row[t] = a;
                if (t == 0){
                    row[25] = s;
                    out0[cid] = clip01(a);
                }
            } else if (t == 26 || t == 27){
                row[t] = 0.f;
            }
        }
        // clear col for next cell (after projection reads it)
        {   float4* c4 = (float4*)col;
            #pragma unroll
            for (int i = 0; i < 8; ++i){ int idx = t + i*64; if (idx < 500) c4[idx] = make_float4(0,0,0,0); } }
    }
}

// ---------------- fused rotate+translate grid_sample + max ----------------
__global__ __launch_bounds__(256)
void final_kernel(const float* __restrict__ ahp,
                  const float* __restrict__ params,
                  const float* __restrict__ maps_last,
                  float* __restrict__ out1){
    int tid = blockIdx.x * blockDim.x + threadIdx.x;
    if (tid >= BS*MC*MC) return;
    int w = tid % MC;
    int h = (tid / MC) % MC;
    int b = tid / (MC*MC);

    float ct = params[b*4+0], st = params[b*4+1];
    float sx = params[b*4+2], sy = params[b*4+3];

    float gx = -1.f + 2.f*(float)w/479.f;
    float gy = -1.f + 2.f*(float)h/479.f;
    float ix = (gx + sx + 1.f)*0.5f*479.f;
    float iy = (gy + sy + 1.f)*0.5f*479.f;
    float x0 = floorf(ix), y0 = floorf(iy);
    float wx1 = ix - x0, wx0 = 1.f - wx1;
    float wy1 = iy - y0, wy0 = 1.f - wy1;

    int   offs[16];
    float wt16[16];
    int nz = 0;
    #pragma unroll
    for (int tc = 0; tc < 4; ++tc){
        float txf = (tc & 1) ? x0 + 1.f : x0;
        float tyf = (tc & 2) ? y0 + 1.f : y0;
        float wt  = ((tc & 1) ? wx1 : wx0) * ((tc & 2) ? wy1 : wy0);
        bool validT = (txf >= 0.f) && (txf <= 479.f) && (tyf >= 0.f) && (tyf <= 479.f);
        int txc = (int)fminf(fmaxf(txf, 0.f), 479.f);
        int tyc = (int)fminf(fmaxf(tyf, 0.f), 479.f);

        float gx2 = -1.f + 2.f*(float)txc/479.f;
        float gy2 = -1.f + 2.f*(float)tyc/479.f;
        float rgx = ct*gx2 - st*gy2;
        float rgy = st*gx2 + ct*gy2;
        float ixr = (rgx + 1.f)*0.5f*479.f;
        float iyr = (rgy + 1.f)*0.5f*479.f;
        float rx0 = floorf(ixr), ry0 = floorf(iyr);
        float rwx1 = ixr - rx0, rwx0 = 1.f - rwx1;
        float rwy1 = iyr - ry0, rwy0 = 1.f - rwy1;

        #pragma unroll
        for (int rc = 0; rc < 4; ++rc){
            int id = tc*4 + rc;
            float rxf = (rc & 1) ? rx0 + 1.f : rx0;
            float ryf = (rc & 2) ? ry0 + 1.f : ry0;
            float wr  = ((rc & 1) ? rwx1 : rwx0) * ((rc & 2) ? rwy1 : rwy0);
            bool validR = (rxf >= 0.f) && (rxf <= 479.f) && (ryf >= 0.f) && (ryf <= 479.f);
            int rxc = (int)fminf(fmaxf(rxf, 0.f), 479.f);
            int ryc = (int)fminf(fmaxf(ryf, 0.f), 479.f);
            bool inwin = validT && validR &&
                         (rxc >= 190) && (rxc < 290) && (ryc >= 240) && (ryc < 336);
            float wgt = wt * wr;
            if (inwin && wgt != 0.f){
                offs[id] = (ryc - 240)*VR + (rxc - 190);
                wt16[id] = wgt;
                nz++;
            } else {
                offs[id] = -1;
                wt16[id] = 0.f;
            }
        }
    }

    size_t outBase = (size_t)b*CC*MC*MC + (size_t)h*MC + w;
    if (nz == 0){
        #pragma unroll
        for (int ch = 0; ch < CC; ++ch){
            size_t o = outBase + (size_t)ch*MC*MC;
            out1[o] = fmaxf(maps_last[o], 0.f);
        }
        return;
    }

    const float* ahp_b = ahp + (size_t)b*NCELL*ROWS;
    float acc[26];
    #pragma unroll
    for (int k = 0; k < 26; ++k) acc[k] = 0.f;

    #pragma unroll
    for (int id = 0; id < 16; ++id){
        if (offs[id] < 0) continue;
        float v[28];
        {
            const float4* rp = (const float4*)(ahp_b + (size_t)offs[id]*ROWS);
            #pragma unroll
            for (int k = 0; k < 7; ++k){
                float4 r = rp[k];
                v[4*k]   = r.x; v[4*k+1] = r.y;
                v[4*k+2] = r.z; v[4*k+3] = r.w;
            }
        }
        float wgt = wt16[id];
        acc[0] += wgt * clip01(v[0]);       // fp_map_pred channel
        acc[1] += wgt * clip01(v[25]);      // exp_pred channel (all-height sum)
        #pragma unroll
        for (int ff = 1; ff < 25; ++ff)
            acc[1+ff] += wgt * clip01(v[ff] / 5.f);
    }

    #pragma unroll
    for (int ch = 0; ch < CC; ++ch){
        float a;
        if (ch == 0)      a = acc[0];
        else if (ch == 1) a = acc[1];
        else if (ch < 4)  a = 0.f;
        else              a = acc[ch-2];    // ch>=4 -> acc[1+(ch-3)]
        size_t o = outBase + (size_t)ch*MC*MC;
        out1[o] = fmaxf(maps_last[o], a);
    }
}

extern "C" void kernel_launch(void* const* d_in, const int* in_sizes, int n_in,
                              void* d_out, int out_size, void* d_ws, size_t ws_size,
                              hipStream_t stream){
    const float* obs         = (const float*)d_in[0];
    const float* pose_obs    = (const float*)d_in[1];
    const float* maps_last   = (const float*)d_in[2];
    const float* poses_last  = (const float*)d_in[3];
    const float* view_angles = (const float*)d_in[4];
    float* out = (float*)d_out;

    const size_t OUT0 = (size_t)BS*VR*VR;        // 40000
    const size_t OUT1 = (size_t)BS*CC*MC*MC;     // 25,804,800
    float* out0 = out;
    float* out1 = out + OUT0;
    float* out2 = out + OUT0 + OUT1;
    float* out3 = out2 + BS*3;

    const size_t AHP_FLOATS  = (size_t)BS*NCELL*ROWS; // 1,120,000 (4.48 MB)
    const size_t NCID        = (size_t)BS*NCELL;      // 40,000
    const size_t FEAT_FLOATS = (size_t)BS*NPIX*FSTR;  // 9,830,400 (39.3 MB)
    const size_t CS_INTS     = NSTRIP + 1;            // 8193

    // small arrays read by final_kernel — always in ws
    float* ahp    = (float*)d_ws;
    float* params = ahp + AHP_FLOATS;
    char*  ws_tail = (char*)(params + 16);
    size_t ws_used_small = (size_t)(ws_tail - (char*)d_ws);

    // big transient arrays: counts + bases(TOT+1) + cursor + cell_start + records + feat
    const size_t BIG_BYTES = (NCID*3 + 1 + CS_INTS)*4 + 64 + NREC_MAX*16 + FEAT_FLOATS*4;
    char* big;
    if (ws_size >= ws_used_small + BIG_BYTES){
        big = ws_tail;
    } else {
        // place in the tail of out1 (fully consumed before final_kernel writes out1)
        big = (char*)(out1 + OUT1) - BIG_BYTES;
        big = (char*)((uintptr_t)big & ~(uintptr_t)15);
    }
    int* counts     = (int*)big;
    int* bases      = counts + NCID;          // NCID+1 entries
    int* cursor     = bases + NCID + 1;
    int* cell_start = cursor + NCID;
    uint4* records = (uint4*)(((uintptr_t)(cell_start + CS_INTS) + 15) & ~(uintptr_t)15);
    float* feat    = (float*)(records + NREC_MAX);

    hipMemsetAsync(counts, 0, NCID*4, stream);
    pose_kernel<<<1, 64, 0, stream>>>(pose_obs, poses_last, out2, out3, params);

    int nblk = (BS*NPIX)/256;   // 1200, exact
    prep_kernel<<<nblk, 256, 0, stream>>>(obs, view_angles, counts, feat);
    scan_kernel<<<1, 1024, 0, stream>>>(counts, bases, cursor, cell_start);
    scatter_kernel<<<nblk, 256, 0, stream>>>(obs, view_angles, cursor, records);
    accum_kernel<<<NSTRIP, 64, 0, stream>>>(records, feat, bases, cell_start,
                                            ahp, out0);
    final_kernel<<<(BS*MC*MC + 255)/256, 256, 0, stream>>>(ahp, params,
                                                           maps_last, out1);
}